// Round 8
// baseline (213.605 us; speedup 1.0000x reference)
//
#include <hip/hip_runtime.h>

#define N_NODES 50000
#define N_EDGES 800000
#define IN_CH 256
#define HID 128
#define LAT 64
#define CAP 64       // bucket slots/node; max in-degree ~45 for random 800k/50k
#define NBIN 196     // ceil(50000/256) bins of 256 nodes
#define BINCAP 4864  // Poisson(4082)+12sigma

typedef __attribute__((ext_vector_type(8))) short short8;
typedef __attribute__((ext_vector_type(16))) float f32x16;

static __device__ __forceinline__ unsigned short bf16_rne(float x) {
    unsigned u = __float_as_uint(x);
    unsigned r = (u + 0x7FFFu + ((u >> 16) & 1u)) >> 16;
    return (unsigned short)r;
}
static __device__ __forceinline__ float bf16_to_f(unsigned short h) {
    return __uint_as_float(((unsigned)h) << 16);
}

static __device__ __forceinline__ void add8(uint4 p, float* a) {
    a[0] += __uint_as_float(p.x << 16);
    a[1] += __uint_as_float(p.x & 0xFFFF0000u);
    a[2] += __uint_as_float(p.y << 16);
    a[3] += __uint_as_float(p.y & 0xFFFF0000u);
    a[4] += __uint_as_float(p.z << 16);
    a[5] += __uint_as_float(p.z & 0xFFFF0000u);
    a[6] += __uint_as_float(p.w << 16);
    a[7] += __uint_as_float(p.w & 0xFFFF0000u);
}
static __device__ __forceinline__ void fma8(uint4 p, float m, float* a) {
    a[0] = fmaf(m, __uint_as_float(p.x << 16), a[0]);
    a[1] = fmaf(m, __uint_as_float(p.x & 0xFFFF0000u), a[1]);
    a[2] = fmaf(m, __uint_as_float(p.y << 16), a[2]);
    a[3] = fmaf(m, __uint_as_float(p.y & 0xFFFF0000u), a[3]);
    a[4] = fmaf(m, __uint_as_float(p.z << 16), a[4]);
    a[5] = fmaf(m, __uint_as_float(p.z & 0xFFFF0000u), a[5]);
    a[6] = fmaf(m, __uint_as_float(p.w << 16), a[6]);
    a[7] = fmaf(m, __uint_as_float(p.w & 0xFFFF0000u), a[7]);
}

// ---------------- prep: zero binCnt + split W1/W2 into bf16 hi/lo planes (fragment order) --
template <int K, int NN>
static __device__ __forceinline__ void split_store(const float* __restrict__ W,
                                                   unsigned short* __restrict__ Wf, int i) {
    constexpr int CT = NN / 32;
    int k = i / NN, n = i % NN;
    float w = W[i];
    unsigned short hi = bf16_rne(w);
    unsigned short lo = bf16_rne(w - bf16_to_f(hi));
    size_t off = ((size_t)((k >> 4) * CT + (n >> 5)) * 64 + ((n & 31) + 32 * ((k >> 3) & 1))) * 8 + (k & 7);
    Wf[off] = hi;
    Wf[(size_t)K * NN + off] = lo;
}

__global__ __launch_bounds__(256) void prep_kernel(const float* __restrict__ W1,
                                                   const float* __restrict__ W2,
                                                   int* __restrict__ binCnt,
                                                   unsigned short* __restrict__ W1f,
                                                   unsigned short* __restrict__ W2f) {
    int i = blockIdx.x * blockDim.x + threadIdx.x;
    if (i < NBIN) binCnt[i] = 0;
    if (i < IN_CH * HID) split_store<IN_CH, HID>(W1, W1f, i);
    if (i < HID * LAT) split_store<HID, LAT>(W2, W2f, i);
}

// ---------------- fill pass 1: bin edges by dst>>8 into fixed-cap regions ----------------
__global__ __launch_bounds__(256) void fill1_kernel(const int* __restrict__ ei,
                                                    int* __restrict__ binCnt,
                                                    unsigned int* __restrict__ binBuf, int E) {
    __shared__ int hist[NBIN];
    __shared__ int base[NBIN];
    const int tid = threadIdx.x;
    for (int i = tid; i < NBIN; i += 256) hist[i] = 0;
    __syncthreads();

    const int e0 = blockIdx.x * 2048 + tid;
    unsigned int pk[8];
    int bn[8], ofs[8];
#pragma unroll
    for (int i = 0; i < 8; ++i) {
        int e = e0 + 256 * i;
        bool v = e < E;
        int s = v ? ei[e] : 0;
        int d = v ? ei[E + e] : 0;
        bn[i] = d >> 8;
        pk[i] = (unsigned int)s | ((unsigned int)(d & 255) << 16);
        ofs[i] = v ? atomicAdd(&hist[bn[i]], 1) : -1;
    }
    __syncthreads();
    for (int i = tid; i < NBIN; i += 256)
        base[i] = hist[i] ? atomicAdd(&binCnt[i], hist[i]) : 0;
    __syncthreads();
#pragma unroll
    for (int i = 0; i < 8; ++i) {
        if (ofs[i] >= 0) {
            int p = base[bn[i]] + ofs[i];
            if (p < BINCAP) binBuf[(size_t)bn[i] * BINCAP + p] = pk[i];
        }
    }
}

// ---------------- fill pass 2: one block per bin builds colb + cnt (single-writer) --------
__global__ __launch_bounds__(256) void fill2_kernel(const int* __restrict__ binCnt,
                                                    const unsigned int* __restrict__ binBuf,
                                                    int* __restrict__ cnt,
                                                    unsigned short* __restrict__ colb) {
    __shared__ int lcnt[256];
    const int b = blockIdx.x;
    const int tid = threadIdx.x;
    lcnt[tid] = 0;
    __syncthreads();
    int n = binCnt[b]; if (n > BINCAP) n = BINCAP;
    const int node0 = b << 8;
    for (int i = tid; i < n; i += 256) {
        unsigned int pk = binBuf[(size_t)b * BINCAP + i];
        int local = pk >> 16;
        int s = pk & 0xFFFF;
        int slot = atomicAdd(&lcnt[local], 1);
        if (slot < CAP) colb[(size_t)(node0 + local) * CAP + slot] = (unsigned short)s;
    }
    __syncthreads();
    int node = node0 + tid;
    if (node < N_NODES) cnt[node] = lcnt[tid];
}

// ---------------- bf16 MFMA GEMM: C[m,:] = bf16(rsqrt(deg+1)[m] * (A@W)[m,:]) ------------
// BM=128, BK=32, 4 waves. A single bf16 plane (AFP32: convert fp32->bf16 in staging;
// else: pure copy-swizzle of bf16 rows). B hi+lo planes pre-swizzled in global, staged
// via global_load_lds width=16. Products: Ah*Bh + Ah*Bl (2 MFMAs).
template <int K, int NN, bool AFP32>
__global__ __launch_bounds__(256) void gemm_kernel(const void* __restrict__ Av,
                                                   const unsigned short* __restrict__ Wf,
                                                   const int* __restrict__ cnt,
                                                   unsigned short* __restrict__ C, int M) {
    constexpr int CT = NN / 32;
    constexpr int MT = (NN == 128) ? 2 : 1;
    __shared__ unsigned short As[8 * 512];           // 2 sl x 4 rowtiles x 1KB = 8KB
    __shared__ unsigned short Bs[2 * 2 * CT * 512];  // 2 planes x 2 sl x CT x 1KB

    const int tid = threadIdx.x;
    const int lane = tid & 63;
    const int w = tid >> 6;
    const int row0 = blockIdx.x * 128;
    const int rtb = (NN == 128) ? ((w >> 1) * 2) : w;
    const int ctb = (NN == 128) ? ((w & 1) * 2) : 0;

    f32x16 acc[MT][2];
#pragma unroll
    for (int mt = 0; mt < MT; ++mt)
#pragma unroll
        for (int nt = 0; nt < 2; ++nt)
#pragma unroll
            for (int q = 0; q < 16; ++q) acc[mt][nt][q] = 0.0f;

    for (int kt = 0; kt < K; kt += 32) {
        // ---- stage A (single bf16 plane, fragment-major) ----
        if constexpr (AFP32) {
            const float* A = (const float*)Av;
#pragma unroll
            for (int i = 0; i < 4; ++i) {
                int f = tid + 256 * i;
                int m = f >> 3, kq = f & 7;
                int row = row0 + m; if (row >= M) row = M - 1;
                const float4 v = *(const float4*)(A + (size_t)row * K + kt + kq * 4);
                ushort4 hi4 = make_ushort4(bf16_rne(v.x), bf16_rne(v.y), bf16_rne(v.z), bf16_rne(v.w));
                int k0 = kq * 4;
                int s = k0 >> 4, half = (k0 >> 3) & 1, j0 = k0 & 7, t = m >> 5;
                int ln = (m & 31) + 32 * half;
                *(ushort4*)&As[((s * 4 + t) << 9) + (ln << 3) + j0] = hi4;
            }
        } else {
            const unsigned short* A = (const unsigned short*)Av;
#pragma unroll
            for (int i = 0; i < 2; ++i) {
                int f = tid + 256 * i;      // 512 chunks of 8 bf16 (128 rows x 4 chunks)
                int m = f >> 2, kc = f & 3;
                int row = row0 + m; if (row >= M) row = M - 1;
                uint4 v = *(const uint4*)(A + (size_t)row * K + kt + kc * 8);
                int s = kc >> 1, half = kc & 1, t = m >> 5;
                int ln = (m & 31) + 32 * half;
                *(uint4*)&As[((s * 4 + t) << 9) + (ln << 3)] = v;
            }
        }
        // ---- stage B: LDS-DMA, wave-uniform base + lane*16 ----
        {
            const int sg0 = kt >> 4;
#pragma unroll
            for (int p = 0; p < 2; ++p)
#pragma unroll
                for (int sl = 0; sl < 2; ++sl) {
                    const float4* src = (const float4*)(Wf + (size_t)p * K * NN + (size_t)(sg0 + sl) * CT * 512);
                    float4* dst = (float4*)(Bs + (((p * 2 + sl) * CT) << 9));
                    for (int c0 = w * 64; c0 < CT * 64; c0 += 256) {
                        __builtin_amdgcn_global_load_lds(
                            (const __attribute__((address_space(1))) unsigned int*)(src + c0 + lane),
                            (__attribute__((address_space(3))) unsigned int*)(dst + c0),
                            16, 0, 0);
                    }
                }
        }
        __syncthreads();

#pragma unroll
        for (int sl = 0; sl < 2; ++sl) {
            short8 a[MT], bh[2], bl[2];
#pragma unroll
            for (int mt = 0; mt < MT; ++mt)
                a[mt] = *(const short8*)&As[((sl * 4 + rtb + mt) << 9) + (lane << 3)];
#pragma unroll
            for (int nt = 0; nt < 2; ++nt) {
                bh[nt] = *(const short8*)&Bs[((sl * CT + ctb + nt) << 9) + (lane << 3)];
                bl[nt] = *(const short8*)&Bs[(((2 + sl) * CT + ctb + nt) << 9) + (lane << 3)];
            }
#pragma unroll
            for (int mt = 0; mt < MT; ++mt)
#pragma unroll
                for (int nt = 0; nt < 2; ++nt) {
                    acc[mt][nt] = __builtin_amdgcn_mfma_f32_32x32x16_bf16(a[mt], bh[nt], acc[mt][nt], 0, 0, 0);
                    acc[mt][nt] = __builtin_amdgcn_mfma_f32_32x32x16_bf16(a[mt], bl[nt], acc[mt][nt], 0, 0, 0);
                }
        }
        __syncthreads();
    }

    // epilogue: scale by rsqrt(deg+1), convert bf16, store
#pragma unroll
    for (int mt = 0; mt < MT; ++mt) {
#pragma unroll
        for (int r = 0; r < 16; ++r) {
            int rowl = (rtb + mt) * 32 + (r & 3) + 8 * (r >> 2) + 4 * (lane >> 5);
            int row = row0 + rowl;
            if (row < M) {
                float sc = rsqrtf((float)cnt[row] + 1.0f);
#pragma unroll
                for (int nt = 0; nt < 2; ++nt) {
                    int col = (ctb + nt) * 32 + (lane & 31);
                    C[(size_t)row * NN + col] = bf16_rne(acc[mt][nt][r] * sc);
                }
            }
        }
    }
}

// ---------------- bucket aggregation over bf16 features ----------------
// out[i] = relu(dis_i*(hs[i]+sum_nbr hs[src]) + b); OBF16 selects bf16 vs fp32 output.
template <int C, bool OBF16>
__global__ __launch_bounds__(256) void agg_kernel(const int* __restrict__ cnt,
                                                  const unsigned short* __restrict__ colb,
                                                  const unsigned short* __restrict__ hs,
                                                  const float* __restrict__ bias,
                                                  void* __restrict__ outv, int N) {
    constexpr int LPN = C / 8;     // 16 for C=128, 8 for C=64
    constexpr int NPW = 64 / LPN;  // 4 / 8
    int node = (int)((blockIdx.x * blockDim.x + threadIdx.x) >> 6);
    int lane = threadIdx.x & 63;
    if (node >= N) return;
    const int g = lane / LPN;
    const int c = lane % LPN;

    int deg = cnt[node];
    int kk = deg < CAP ? deg : CAP;

    float acc[8];
#pragma unroll
    for (int q = 0; q < 8; ++q) acc[q] = 0.0f;
    if (g == 0) add8(*(const uint4*)(hs + (size_t)node * C + c * 8), acc);  // self loop

    int myc = (lane < kk) ? (int)colb[(size_t)node * CAP + lane] : 0;

    int j = 0;
    for (; j + NPW * 4 <= kk; j += NPW * 4) {
        int s0 = __shfl(myc, j + g);
        int s1 = __shfl(myc, j + g + NPW);
        int s2 = __shfl(myc, j + g + 2 * NPW);
        int s3 = __shfl(myc, j + g + 3 * NPW);
        uint4 p0 = *(const uint4*)(hs + (size_t)s0 * C + c * 8);
        uint4 p1 = *(const uint4*)(hs + (size_t)s1 * C + c * 8);
        uint4 p2 = *(const uint4*)(hs + (size_t)s2 * C + c * 8);
        uint4 p3 = *(const uint4*)(hs + (size_t)s3 * C + c * 8);
        add8(p0, acc); add8(p1, acc); add8(p2, acc); add8(p3, acc);
    }
    if (j < kk) {
        bool v0 = (j + g) < kk, v1 = (j + g + NPW) < kk,
             v2 = (j + g + 2 * NPW) < kk, v3 = (j + g + 3 * NPW) < kk;
        int s0 = __shfl(myc, v0 ? (j + g) : 0);
        int s1 = __shfl(myc, v1 ? (j + g + NPW) : 0);
        int s2 = __shfl(myc, v2 ? (j + g + 2 * NPW) : 0);
        int s3 = __shfl(myc, v3 ? (j + g + 3 * NPW) : 0);
        uint4 p0 = *(const uint4*)(hs + (size_t)s0 * C + c * 8);
        uint4 p1 = *(const uint4*)(hs + (size_t)s1 * C + c * 8);
        uint4 p2 = *(const uint4*)(hs + (size_t)s2 * C + c * 8);
        uint4 p3 = *(const uint4*)(hs + (size_t)s3 * C + c * 8);
        fma8(p0, v0 ? 1.0f : 0.0f, acc);
        fma8(p1, v1 ? 1.0f : 0.0f, acc);
        fma8(p2, v2 ? 1.0f : 0.0f, acc);
        fma8(p3, v3 ? 1.0f : 0.0f, acc);
    }

#pragma unroll
    for (int s = LPN; s < 64; s <<= 1)
#pragma unroll
        for (int q = 0; q < 8; ++q) acc[q] += __shfl_xor(acc[q], s);

    if (lane < LPN) {
        float di = rsqrtf((float)deg + 1.0f);
        float o[8];
#pragma unroll
        for (int q = 0; q < 8; ++q)
            o[q] = fmaxf(fmaf(di, acc[q], bias[c * 8 + q]), 0.0f);
        if constexpr (OBF16) {
            unsigned short* out = (unsigned short*)outv;
            ushort4 lo4 = make_ushort4(bf16_rne(o[0]), bf16_rne(o[1]), bf16_rne(o[2]), bf16_rne(o[3]));
            ushort4 hi4 = make_ushort4(bf16_rne(o[4]), bf16_rne(o[5]), bf16_rne(o[6]), bf16_rne(o[7]));
            *(ushort4*)(out + (size_t)node * C + c * 8) = lo4;
            *(ushort4*)(out + (size_t)node * C + c * 8 + 4) = hi4;
        } else {
            float* out = (float*)outv;
            float4 o0 = {o[0], o[1], o[2], o[3]};
            float4 o1 = {o[4], o[5], o[6], o[7]};
            *(float4*)(out + (size_t)node * C + c * 8) = o0;
            *(float4*)(out + (size_t)node * C + c * 8 + 4) = o1;
        }
    }
}

extern "C" void kernel_launch(void* const* d_in, const int* in_sizes, int n_in,
                              void* d_out, int out_size, void* d_ws, size_t ws_size,
                              hipStream_t stream) {
    const float* x  = (const float*)d_in[0];
    const int*   ei = (const int*)d_in[1];
    const float* W1 = (const float*)d_in[2];
    const float* b1 = (const float*)d_in[3];
    const float* W2 = (const float*)d_in[4];
    const float* b2 = (const float*)d_in[5];

    const int N = N_NODES, E = N_EDGES;

    char* ws = (char*)d_ws;
    size_t off = 0;
    auto alloc = [&](size_t bytes) {
        void* p = ws + off;
        off = (off + bytes + 255) & ~(size_t)255;
        return p;
    };
    int*            cnt    = (int*)alloc((size_t)N * 4);                   // 200 KB
    unsigned short* colb   = (unsigned short*)alloc((size_t)N * CAP * 2);  // 6.4 MB
    int*            binCnt = (int*)alloc((size_t)NBIN * 4);
    unsigned int*   binBuf = (unsigned int*)alloc((size_t)NBIN * BINCAP * 4);  // 3.8 MB
    unsigned short* W1f    = (unsigned short*)alloc((size_t)2 * IN_CH * HID * 2);  // 128 KB
    unsigned short* W2f    = (unsigned short*)alloc((size_t)2 * HID * LAT * 2);    // 32 KB
    unsigned short* h1s    = (unsigned short*)alloc((size_t)N * HID * 2);  // 12.8 MB bf16
    unsigned short* act1   = (unsigned short*)alloc((size_t)N * HID * 2);  // 12.8 MB bf16
    unsigned short* h2s    = h1s;  // h1s dead after agg1 (needs 6.4 MB, slot has 12.8)

    prep_kernel<<<(N + 255) / 256, 256, 0, stream>>>(W1, W2, binCnt, W1f, W2f);
    fill1_kernel<<<(E + 2047) / 2048, 256, 0, stream>>>(ei, binCnt, binBuf, E);
    fill2_kernel<<<NBIN, 256, 0, stream>>>(binCnt, binBuf, cnt, colb);

    // layer 1: h1s = bf16(dis*(x@W1)); act1 = bf16(relu(dis*(self+nbrs) + b1))
    gemm_kernel<IN_CH, HID, true><<<(N + 127) / 128, 256, 0, stream>>>(x, W1f, cnt, h1s, N);
    agg_kernel<HID, true><<<(N + 3) / 4, 256, 0, stream>>>(cnt, colb, h1s, b1, act1, N);

    // layer 2: h2s = bf16(dis*(act1@W2)); out = relu(dis*(self+nbrs) + b2)  [fp32]
    gemm_kernel<HID, LAT, false><<<(N + 127) / 128, 256, 0, stream>>>(act1, W2f, cnt, h2s, N);
    agg_kernel<LAT, false><<<(N + 3) / 4, 256, 0, stream>>>(cnt, colb, h2s, b2, d_out, N);
}

// Round 9
// 198.267 us; speedup vs baseline: 1.0774x; 1.0774x over previous
//
#include <hip/hip_runtime.h>

#define N_NODES 50000
#define N_EDGES 800000
#define IN_CH 256
#define HID 128
#define LAT 64
#define CAP 64       // bucket slots/node; max in-degree ~45 for random 800k/50k
#define NBIN 196     // ceil(50000/256) bins of 256 nodes
#define BINCAP 4864  // Poisson(4082)+12sigma

typedef __attribute__((ext_vector_type(8))) short short8;
typedef __attribute__((ext_vector_type(16))) float f32x16;

static __device__ __forceinline__ unsigned short bf16_rne(float x) {
    unsigned u = __float_as_uint(x);
    unsigned r = (u + 0x7FFFu + ((u >> 16) & 1u)) >> 16;
    return (unsigned short)r;
}
static __device__ __forceinline__ float bf16_to_f(unsigned short h) {
    return __uint_as_float(((unsigned)h) << 16);
}

static __device__ __forceinline__ void add8(uint4 p, float* a) {
    a[0] += __uint_as_float(p.x << 16);
    a[1] += __uint_as_float(p.x & 0xFFFF0000u);
    a[2] += __uint_as_float(p.y << 16);
    a[3] += __uint_as_float(p.y & 0xFFFF0000u);
    a[4] += __uint_as_float(p.z << 16);
    a[5] += __uint_as_float(p.z & 0xFFFF0000u);
    a[6] += __uint_as_float(p.w << 16);
    a[7] += __uint_as_float(p.w & 0xFFFF0000u);
}
static __device__ __forceinline__ void fma8(uint4 p, float m, float* a) {
    a[0] = fmaf(m, __uint_as_float(p.x << 16), a[0]);
    a[1] = fmaf(m, __uint_as_float(p.x & 0xFFFF0000u), a[1]);
    a[2] = fmaf(m, __uint_as_float(p.y << 16), a[2]);
    a[3] = fmaf(m, __uint_as_float(p.y & 0xFFFF0000u), a[3]);
    a[4] = fmaf(m, __uint_as_float(p.z << 16), a[4]);
    a[5] = fmaf(m, __uint_as_float(p.z & 0xFFFF0000u), a[5]);
    a[6] = fmaf(m, __uint_as_float(p.w << 16), a[6]);
    a[7] = fmaf(m, __uint_as_float(p.w & 0xFFFF0000u), a[7]);
}

// ---------------- prep: zero binCnt + split W1/W2 into bf16 hi/lo planes (fragment order) --
template <int K, int NN>
static __device__ __forceinline__ void split_store(const float* __restrict__ W,
                                                   unsigned short* __restrict__ Wf, int i) {
    constexpr int CT = NN / 32;
    int k = i / NN, n = i % NN;
    float w = W[i];
    unsigned short hi = bf16_rne(w);
    unsigned short lo = bf16_rne(w - bf16_to_f(hi));
    size_t off = ((size_t)((k >> 4) * CT + (n >> 5)) * 64 + ((n & 31) + 32 * ((k >> 3) & 1))) * 8 + (k & 7);
    Wf[off] = hi;
    Wf[(size_t)K * NN + off] = lo;
}

__global__ __launch_bounds__(256) void prep_kernel(const float* __restrict__ W1,
                                                   const float* __restrict__ W2,
                                                   int* __restrict__ binCnt,
                                                   unsigned short* __restrict__ W1f,
                                                   unsigned short* __restrict__ W2f) {
    int i = blockIdx.x * blockDim.x + threadIdx.x;
    if (i < NBIN) binCnt[i] = 0;
    if (i < IN_CH * HID) split_store<IN_CH, HID>(W1, W1f, i);
    if (i < HID * LAT) split_store<HID, LAT>(W2, W2f, i);
}

// ---------------- fill pass 1: bin edges by dst>>8 into fixed-cap regions ----------------
__global__ __launch_bounds__(256) void fill1_kernel(const int* __restrict__ ei,
                                                    int* __restrict__ binCnt,
                                                    unsigned int* __restrict__ binBuf, int E) {
    __shared__ int hist[NBIN];
    __shared__ int base[NBIN];
    const int tid = threadIdx.x;
    for (int i = tid; i < NBIN; i += 256) hist[i] = 0;
    __syncthreads();

    const int e0 = blockIdx.x * 2048 + tid;
    unsigned int pk[8];
    int bn[8], ofs[8];
#pragma unroll
    for (int i = 0; i < 8; ++i) {
        int e = e0 + 256 * i;
        bool v = e < E;
        int s = v ? ei[e] : 0;
        int d = v ? ei[E + e] : 0;
        bn[i] = d >> 8;
        pk[i] = (unsigned int)s | ((unsigned int)(d & 255) << 16);
        ofs[i] = v ? atomicAdd(&hist[bn[i]], 1) : -1;
    }
    __syncthreads();
    for (int i = tid; i < NBIN; i += 256)
        base[i] = hist[i] ? atomicAdd(&binCnt[i], hist[i]) : 0;
    __syncthreads();
#pragma unroll
    for (int i = 0; i < 8; ++i) {
        if (ofs[i] >= 0) {
            int p = base[bn[i]] + ofs[i];
            if (p < BINCAP) binBuf[(size_t)bn[i] * BINCAP + p] = pk[i];
        }
    }
}

// ---------------- fill pass 2: one block per bin builds colb + cnt (single-writer) --------
__global__ __launch_bounds__(256) void fill2_kernel(const int* __restrict__ binCnt,
                                                    const unsigned int* __restrict__ binBuf,
                                                    int* __restrict__ cnt,
                                                    unsigned short* __restrict__ colb) {
    __shared__ int lcnt[256];
    const int b = blockIdx.x;
    const int tid = threadIdx.x;
    lcnt[tid] = 0;
    __syncthreads();
    int n = binCnt[b]; if (n > BINCAP) n = BINCAP;
    const int node0 = b << 8;
    for (int i = tid; i < n; i += 256) {
        unsigned int pk = binBuf[(size_t)b * BINCAP + i];
        int local = pk >> 16;
        int s = pk & 0xFFFF;
        int slot = atomicAdd(&lcnt[local], 1);
        if (slot < CAP) colb[(size_t)(node0 + local) * CAP + slot] = (unsigned short)s;
    }
    __syncthreads();
    int node = node0 + tid;
    if (node < N_NODES) cnt[node] = lcnt[tid];
}

// ---------------- bf16 MFMA GEMM: C[m,:] = bf16(rsqrt(deg+1)[m] * (A@W)[m,:]) ------------
// BM=64, BK=32, 4 waves -> 782 blocks (~3/CU for latency hiding through barriers).
// Wave tile: NN=128: 32 rows x 64 cols (rt=w>>1, ct0=(w&1)*2, NT=2);
//            NN=64:  32 rows x 32 cols (rt=w>>1, ct0=w&1,     NT=1).
// A single bf16 plane (AFP32: fp32->bf16 in staging; else pure copy-swizzle), 16B LDS stores.
// B hi+lo planes pre-swizzled in global, staged with plain float4 loads.
template <int K, int NN, bool AFP32>
__global__ __launch_bounds__(256) void gemm_kernel(const void* __restrict__ Av,
                                                   const unsigned short* __restrict__ Wf,
                                                   const int* __restrict__ cnt,
                                                   unsigned short* __restrict__ C, int M) {
    constexpr int CT = NN / 32;                 // col tiles (4 / 2)
    constexpr int NT = (NN == 128) ? 2 : 1;     // col tiles per wave
    __shared__ unsigned short As[4 * 512];           // 2 sl x 2 rowtiles x 1KB = 4KB
    __shared__ unsigned short Bs[2 * 2 * CT * 512];  // planes x sl x CT x 1KB (16/8 KB)

    const int tid = threadIdx.x;
    const int lane = tid & 63;
    const int w = tid >> 6;
    const int row0 = blockIdx.x * 64;
    const int rt = w >> 1;                        // rowtile (32 rows)
    const int ct0 = (NN == 128) ? ((w & 1) * 2) : (w & 1);

    f32x16 acc[NT];
#pragma unroll
    for (int nt = 0; nt < NT; ++nt)
#pragma unroll
        for (int q = 0; q < 16; ++q) acc[nt][q] = 0.0f;

    for (int kt = 0; kt < K; kt += 32) {
        // ---- stage A: 64 rows x 32 k, single bf16 plane, 16B stores ----
        {
            int m = tid >> 2, kc = tid & 3;       // row, 8-k chunk
            int row = row0 + m; if (row >= M) row = M - 1;
            int s = kc >> 1, half = kc & 1, t = m >> 5;
            int ln = (m & 31) + 32 * half;
            uint4 v;
            if constexpr (AFP32) {
                const float* A = (const float*)Av;
                const float4 v0 = *(const float4*)(A + (size_t)row * K + kt + kc * 8);
                const float4 v1 = *(const float4*)(A + (size_t)row * K + kt + kc * 8 + 4);
                v.x = (unsigned)bf16_rne(v0.x) | ((unsigned)bf16_rne(v0.y) << 16);
                v.y = (unsigned)bf16_rne(v0.z) | ((unsigned)bf16_rne(v0.w) << 16);
                v.z = (unsigned)bf16_rne(v1.x) | ((unsigned)bf16_rne(v1.y) << 16);
                v.w = (unsigned)bf16_rne(v1.z) | ((unsigned)bf16_rne(v1.w) << 16);
            } else {
                const unsigned short* A = (const unsigned short*)Av;
                v = *(const uint4*)(A + (size_t)row * K + kt + kc * 8);
            }
            *(uint4*)&As[((s * 2 + t) << 9) + (ln << 3)] = v;
        }
        // ---- stage B: plain vector copy (pre-swizzled in global) ----
        {
            const int sg0 = kt >> 4;
#pragma unroll
            for (int i0 = 0; i0 < CT * 256; i0 += 256) {
                int i = i0 + tid;
                int psl = i / (CT * 64), rem = i % (CT * 64);
                int p = psl >> 1, sl = psl & 1;
                const uint4* src = (const uint4*)(Wf + (size_t)p * K * NN + (size_t)(sg0 + sl) * CT * 512);
                ((uint4*)Bs)[i] = src[rem];
            }
        }
        __syncthreads();

#pragma unroll
        for (int sl = 0; sl < 2; ++sl) {
            short8 a = *(const short8*)&As[((sl * 2 + rt) << 9) + (lane << 3)];
            short8 bh[NT], bl[NT];
#pragma unroll
            for (int nt = 0; nt < NT; ++nt) {
                bh[nt] = *(const short8*)&Bs[((sl * CT + ct0 + nt) << 9) + (lane << 3)];
                bl[nt] = *(const short8*)&Bs[(((2 + sl) * CT + ct0 + nt) << 9) + (lane << 3)];
            }
#pragma unroll
            for (int nt = 0; nt < NT; ++nt) {
                acc[nt] = __builtin_amdgcn_mfma_f32_32x32x16_bf16(a, bh[nt], acc[nt], 0, 0, 0);
                acc[nt] = __builtin_amdgcn_mfma_f32_32x32x16_bf16(a, bl[nt], acc[nt], 0, 0, 0);
            }
        }
        __syncthreads();
    }

    // epilogue: scale by rsqrt(deg+1), convert bf16, store
#pragma unroll
    for (int r = 0; r < 16; ++r) {
        int rowl = rt * 32 + (r & 3) + 8 * (r >> 2) + 4 * (lane >> 5);
        int row = row0 + rowl;
        if (row < M) {
            float sc = rsqrtf((float)cnt[row] + 1.0f);
#pragma unroll
            for (int nt = 0; nt < NT; ++nt) {
                int col = (ct0 + nt) * 32 + (lane & 31);
                C[(size_t)row * NN + col] = bf16_rne(acc[nt][r] * sc);
            }
        }
    }
}

// ---------------- bucket aggregation over bf16 features ----------------
// out[i] = relu(dis_i*(hs[i]+sum_nbr hs[src]) + b); OBF16 selects bf16 vs fp32 output.
template <int C, bool OBF16>
__global__ __launch_bounds__(256) void agg_kernel(const int* __restrict__ cnt,
                                                  const unsigned short* __restrict__ colb,
                                                  const unsigned short* __restrict__ hs,
                                                  const float* __restrict__ bias,
                                                  void* __restrict__ outv, int N) {
    constexpr int LPN = C / 8;     // 16 for C=128, 8 for C=64
    constexpr int NPW = 64 / LPN;  // 4 / 8
    int node = (int)((blockIdx.x * blockDim.x + threadIdx.x) >> 6);
    int lane = threadIdx.x & 63;
    if (node >= N) return;
    const int g = lane / LPN;
    const int c = lane % LPN;

    int deg = cnt[node];
    int kk = deg < CAP ? deg : CAP;

    float acc[8];
#pragma unroll
    for (int q = 0; q < 8; ++q) acc[q] = 0.0f;
    if (g == 0) add8(*(const uint4*)(hs + (size_t)node * C + c * 8), acc);  // self loop

    int myc = (lane < kk) ? (int)colb[(size_t)node * CAP + lane] : 0;

    int j = 0;
    for (; j + NPW * 4 <= kk; j += NPW * 4) {
        int s0 = __shfl(myc, j + g);
        int s1 = __shfl(myc, j + g + NPW);
        int s2 = __shfl(myc, j + g + 2 * NPW);
        int s3 = __shfl(myc, j + g + 3 * NPW);
        uint4 p0 = *(const uint4*)(hs + (size_t)s0 * C + c * 8);
        uint4 p1 = *(const uint4*)(hs + (size_t)s1 * C + c * 8);
        uint4 p2 = *(const uint4*)(hs + (size_t)s2 * C + c * 8);
        uint4 p3 = *(const uint4*)(hs + (size_t)s3 * C + c * 8);
        add8(p0, acc); add8(p1, acc); add8(p2, acc); add8(p3, acc);
    }
    if (j < kk) {
        bool v0 = (j + g) < kk, v1 = (j + g + NPW) < kk,
             v2 = (j + g + 2 * NPW) < kk, v3 = (j + g + 3 * NPW) < kk;
        int s0 = __shfl(myc, v0 ? (j + g) : 0);
        int s1 = __shfl(myc, v1 ? (j + g + NPW) : 0);
        int s2 = __shfl(myc, v2 ? (j + g + 2 * NPW) : 0);
        int s3 = __shfl(myc, v3 ? (j + g + 3 * NPW) : 0);
        uint4 p0 = *(const uint4*)(hs + (size_t)s0 * C + c * 8);
        uint4 p1 = *(const uint4*)(hs + (size_t)s1 * C + c * 8);
        uint4 p2 = *(const uint4*)(hs + (size_t)s2 * C + c * 8);
        uint4 p3 = *(const uint4*)(hs + (size_t)s3 * C + c * 8);
        fma8(p0, v0 ? 1.0f : 0.0f, acc);
        fma8(p1, v1 ? 1.0f : 0.0f, acc);
        fma8(p2, v2 ? 1.0f : 0.0f, acc);
        fma8(p3, v3 ? 1.0f : 0.0f, acc);
    }

#pragma unroll
    for (int s = LPN; s < 64; s <<= 1)
#pragma unroll
        for (int q = 0; q < 8; ++q) acc[q] += __shfl_xor(acc[q], s);

    if (lane < LPN) {
        float di = rsqrtf((float)deg + 1.0f);
        float o[8];
#pragma unroll
        for (int q = 0; q < 8; ++q)
            o[q] = fmaxf(fmaf(di, acc[q], bias[c * 8 + q]), 0.0f);
        if constexpr (OBF16) {
            unsigned short* out = (unsigned short*)outv;
            ushort4 lo4 = make_ushort4(bf16_rne(o[0]), bf16_rne(o[1]), bf16_rne(o[2]), bf16_rne(o[3]));
            ushort4 hi4 = make_ushort4(bf16_rne(o[4]), bf16_rne(o[5]), bf16_rne(o[6]), bf16_rne(o[7]));
            *(ushort4*)(out + (size_t)node * C + c * 8) = lo4;
            *(ushort4*)(out + (size_t)node * C + c * 8 + 4) = hi4;
        } else {
            float* out = (float*)outv;
            float4 o0 = {o[0], o[1], o[2], o[3]};
            float4 o1 = {o[4], o[5], o[6], o[7]};
            *(float4*)(out + (size_t)node * C + c * 8) = o0;
            *(float4*)(out + (size_t)node * C + c * 8 + 4) = o1;
        }
    }
}

extern "C" void kernel_launch(void* const* d_in, const int* in_sizes, int n_in,
                              void* d_out, int out_size, void* d_ws, size_t ws_size,
                              hipStream_t stream) {
    const float* x  = (const float*)d_in[0];
    const int*   ei = (const int*)d_in[1];
    const float* W1 = (const float*)d_in[2];
    const float* b1 = (const float*)d_in[3];
    const float* W2 = (const float*)d_in[4];
    const float* b2 = (const float*)d_in[5];

    const int N = N_NODES, E = N_EDGES;

    char* ws = (char*)d_ws;
    size_t off = 0;
    auto alloc = [&](size_t bytes) {
        void* p = ws + off;
        off = (off + bytes + 255) & ~(size_t)255;
        return p;
    };
    int*            cnt    = (int*)alloc((size_t)N * 4);                   // 200 KB
    unsigned short* colb   = (unsigned short*)alloc((size_t)N * CAP * 2);  // 6.4 MB
    int*            binCnt = (int*)alloc((size_t)NBIN * 4);
    unsigned int*   binBuf = (unsigned int*)alloc((size_t)NBIN * BINCAP * 4);  // 3.8 MB
    unsigned short* W1f    = (unsigned short*)alloc((size_t)2 * IN_CH * HID * 2);  // 128 KB
    unsigned short* W2f    = (unsigned short*)alloc((size_t)2 * HID * LAT * 2);    // 32 KB
    unsigned short* h1s    = (unsigned short*)alloc((size_t)N * HID * 2);  // 12.8 MB bf16
    unsigned short* act1   = (unsigned short*)alloc((size_t)N * HID * 2);  // 12.8 MB bf16
    unsigned short* h2s    = h1s;  // h1s dead after agg1 (needs 6.4 MB, slot has 12.8)

    prep_kernel<<<(N + 255) / 256, 256, 0, stream>>>(W1, W2, binCnt, W1f, W2f);
    fill1_kernel<<<(E + 2047) / 2048, 256, 0, stream>>>(ei, binCnt, binBuf, E);
    fill2_kernel<<<NBIN, 256, 0, stream>>>(binCnt, binBuf, cnt, colb);

    // layer 1: h1s = bf16(dis*(x@W1)); act1 = bf16(relu(dis*(self+nbrs) + b1))
    gemm_kernel<IN_CH, HID, true><<<(N + 63) / 64, 256, 0, stream>>>(x, W1f, cnt, h1s, N);
    agg_kernel<HID, true><<<(N + 3) / 4, 256, 0, stream>>>(cnt, colb, h1s, b1, act1, N);

    // layer 2: h2s = bf16(dis*(act1@W2)); out = relu(dis*(self+nbrs) + b2)  [fp32]
    gemm_kernel<HID, LAT, false><<<(N + 63) / 64, 256, 0, stream>>>(act1, W2f, cnt, h2s, N);
    agg_kernel<LAT, false><<<(N + 3) / 4, 256, 0, stream>>>(cnt, colb, h2s, b2, d_out, N);
}